// Round 4
// baseline (1093.270 us; speedup 1.0000x reference)
//
#include <hip/hip_runtime.h>
#include <hip/hip_bf16.h>

// Problem constants
#define NT    4096   // B*T tokens
#define DIMC  512    // model dim
#define DQ    1024   // DIM_QUERY
#define NH    4      // heads
#define DH    128    // head dim
#define NKEY  256
#define TK    32

// ---------------------------------------------------------------------------
// K1: Q projection in f32 with sequential FMA chain over c ascending (mirrors
// BLAS/Eigen sgemm microkernel rounding), + fused LayerNorm epilogue (f64 on
// the f32 q values — LN arithmetic is flip-immaterial). Output f32.
// ---------------------------------------------------------------------------
__global__ __launch_bounds__(256) void k_qproj_ln(
    const float* __restrict__ x, const float* __restrict__ wq,
    const float* __restrict__ ln_g, const float* __restrict__ ln_b,
    float* __restrict__ qn) {
  const int bm = blockIdx.x * 64;        // token tile
  const int nb = blockIdx.y;             // 0..7 -> 128-dim (p,h) group
  const int n0 = nb * 128;
  const int tid = threadIdx.x;
  const int tx = tid & 15;               // 16 col-groups (8 cols each)
  const int ty = tid >> 4;               // 16 row-groups (4 rows each)

  __shared__ __align__(16) float As[16][68];   // [k][m], padded
  __shared__ __align__(16) float Bs[16][130];  // [k][n], padded

  float acc[4][8];
#pragma unroll
  for (int r = 0; r < 4; ++r)
#pragma unroll
    for (int c = 0; c < 8; ++c) acc[r][c] = 0.0f;

  for (int k0 = 0; k0 < DIMC; k0 += 16) {
    {
      int row = tid >> 2, kg = tid & 3;
      float4 v = *reinterpret_cast<const float4*>(
          &x[(size_t)(bm + row) * DIMC + k0 + kg * 4]);
      As[kg * 4 + 0][row] = v.x; As[kg * 4 + 1][row] = v.y;
      As[kg * 4 + 2][row] = v.z; As[kg * 4 + 3][row] = v.w;
    }
#pragma unroll
    for (int it = 0; it < 2; ++it) {
      int idx = it * 256 + tid;
      int rn = idx >> 2, kg = idx & 3;
      float4 v = *reinterpret_cast<const float4*>(
          &wq[(size_t)(n0 + rn) * DIMC + k0 + kg * 4]);
      Bs[kg * 4 + 0][rn] = v.x; Bs[kg * 4 + 1][rn] = v.y;
      Bs[kg * 4 + 2][rn] = v.z; Bs[kg * 4 + 3][rn] = v.w;
    }
    __syncthreads();
#pragma unroll
    for (int kk = 0; kk < 16; ++kk) {   // k ascending: chain order preserved
      float4 a4 = *reinterpret_cast<const float4*>(&As[kk][ty * 4]);
      float2 bp0 = *reinterpret_cast<const float2*>(&Bs[kk][2 * tx]);
      float2 bp1 = *reinterpret_cast<const float2*>(&Bs[kk][2 * tx + 32]);
      float2 bp2 = *reinterpret_cast<const float2*>(&Bs[kk][2 * tx + 64]);
      float2 bp3 = *reinterpret_cast<const float2*>(&Bs[kk][2 * tx + 96]);
      float af[4] = {a4.x, a4.y, a4.z, a4.w};
      float bf[8] = {bp0.x, bp0.y, bp1.x, bp1.y, bp2.x, bp2.y, bp3.x, bp3.y};
#pragma unroll
      for (int r = 0; r < 4; ++r)
#pragma unroll
        for (int c = 0; c < 8; ++c)
          acc[r][c] = fmaf(af[r], bf[c], acc[r][c]);
    }
    __syncthreads();
  }

  // LayerNorm epilogue (f64 math on the f32 q values; flip-immaterial).
  double gg[8], bb[8];
#pragma unroll
  for (int c = 0; c < 8; ++c) {
    int d = 2 * tx + 32 * (c >> 1) + (c & 1);
    gg[c] = (double)ln_g[d]; bb[c] = (double)ln_b[d];
  }
#pragma unroll
  for (int r = 0; r < 4; ++r) {
    double qf[8];
#pragma unroll
    for (int c = 0; c < 8; ++c) qf[c] = (double)acc[r][c];
    double s = 0.0;
#pragma unroll
    for (int c = 0; c < 8; ++c) s += qf[c];
#pragma unroll
    for (int m = 1; m < 16; m <<= 1) s += __shfl_xor(s, m, 64);
    double mu = s * (1.0 / 128.0);
    double vs = 0.0;
#pragma unroll
    for (int c = 0; c < 8; ++c) { double d = qf[c] - mu; vs += d * d; }
#pragma unroll
    for (int m = 1; m < 16; m <<= 1) vs += __shfl_xor(vs, m, 64);
    double rstd = 1.0 / sqrt(vs * (1.0 / 128.0) + 1e-5);
    float* o = &qn[(size_t)(bm + ty * 4 + r) * DQ + n0];
#pragma unroll
    for (int cp = 0; cp < 4; ++cp) {
      float2 st;
      st.x = (float)((qf[2 * cp] - mu) * rstd * gg[2 * cp] + bb[2 * cp]);
      st.y = (float)((qf[2 * cp + 1] - mu) * rstd * gg[2 * cp + 1] + bb[2 * cp + 1]);
      *reinterpret_cast<float2*>(&o[2 * tx + 32 * cp]) = st;
    }
  }
}

// ---------------------------------------------------------------------------
// K2: dots for head h in f32 sequential-FMA over d ascending.
// sc[(t*2+p)*256+n] = sum_d qn[t,p,h,d]*keys[h,n,p,d]
// ---------------------------------------------------------------------------
__global__ __launch_bounds__(256) void k_dots(
    const float* __restrict__ qn, const float* __restrict__ keys,
    float* __restrict__ sc, int h) {
  const int t0 = blockIdx.x * 32;
  const int p = blockIdx.y;
  const int qoff = p * 512 + h * 128;
  const int tid = threadIdx.x;
  const int tx = tid & 31;   // 32 col-groups (8 cols each -> 256)
  const int ty = tid >> 5;   // 8 row-groups (4 rows each -> 32)

  __shared__ __align__(16) float Asf[32][36];   // [k][m] padded
  __shared__ __align__(16) float Bs[32][258];   // [k][n] padded

  float acc[4][8];
#pragma unroll
  for (int r = 0; r < 4; ++r)
#pragma unroll
    for (int c = 0; c < 8; ++c) acc[r][c] = 0.0f;

  for (int k0 = 0; k0 < DH; k0 += 32) {
    {
      int m = tid >> 3, kg = tid & 7;
      float4 v = *reinterpret_cast<const float4*>(
          &qn[(size_t)(t0 + m) * DQ + qoff + k0 + kg * 4]);
      Asf[kg * 4 + 0][m] = v.x; Asf[kg * 4 + 1][m] = v.y;
      Asf[kg * 4 + 2][m] = v.z; Asf[kg * 4 + 3][m] = v.w;
    }
#pragma unroll
    for (int it = 0; it < 8; ++it) {
      int idx = it * 256 + tid;
      int n = idx >> 3, kg = idx & 7;
      float4 v = *reinterpret_cast<const float4*>(
          &keys[(size_t)((h * NKEY + n) * 2 + p) * DH + k0 + kg * 4]);
      Bs[kg * 4 + 0][n] = v.x; Bs[kg * 4 + 1][n] = v.y;
      Bs[kg * 4 + 2][n] = v.z; Bs[kg * 4 + 3][n] = v.w;
    }
    __syncthreads();
#pragma unroll
    for (int kk = 0; kk < 32; ++kk) {   // d ascending
      float4 a4 = *reinterpret_cast<const float4*>(&Asf[kk][ty * 4]);
      float2 b0 = *reinterpret_cast<const float2*>(&Bs[kk][2 * tx]);
      float2 b1 = *reinterpret_cast<const float2*>(&Bs[kk][2 * tx + 64]);
      float2 b2 = *reinterpret_cast<const float2*>(&Bs[kk][2 * tx + 128]);
      float2 b3 = *reinterpret_cast<const float2*>(&Bs[kk][2 * tx + 192]);
      float af[4] = {a4.x, a4.y, a4.z, a4.w};
      float bf[8] = {b0.x, b0.y, b1.x, b1.y, b2.x, b2.y, b3.x, b3.y};
#pragma unroll
      for (int r = 0; r < 4; ++r)
#pragma unroll
        for (int c = 0; c < 8; ++c)
          acc[r][c] = fmaf(af[r], bf[c], acc[r][c]);
    }
    __syncthreads();
  }

#pragma unroll
  for (int r = 0; r < 4; ++r) {
    float* o = &sc[((size_t)(t0 + ty * 4 + r) * 2 + p) * NKEY];
#pragma unroll
    for (int cp = 0; cp < 4; ++cp) {
      float2 st;
      st.x = acc[r][2 * cp];
      st.y = acc[r][2 * cp + 1];
      *reinterpret_cast<float2*>(&o[2 * tx + 64 * cp]) = st;
    }
  }
}

// ---------------------------------------------------------------------------
// K3: per (token, h): top-k on FP32 values with lax.top_k tie-break (lower
// index first), via packed uint64 keys: (orderable_f32 << 32) | (~index).
// Pair sums computed in FP32 (bitwise-matching the reference's fp32 adds).
// ---------------------------------------------------------------------------
__device__ __forceinline__ unsigned f32_ord(float f) {
  unsigned u = __float_as_uint(f);
  return (u & 0x80000000u) ? ~u : (u | 0x80000000u);
}
__device__ __forceinline__ float f32_unord(unsigned u) {
  unsigned b = (u & 0x80000000u) ? (u & 0x7FFFFFFFu) : ~u;
  return __uint_as_float(b);
}

__global__ __launch_bounds__(256) void k_topk(
    const float* __restrict__ sc, float* __restrict__ wout,
    int* __restrict__ vout, int h) {
  const int t = blockIdx.x;
  const int tid = threadIdx.x;
  __shared__ unsigned long long skey[1024];
  __shared__ float sxf[64];   // [0..31]=sx, [32..63]=sy (sorted desc)
  __shared__ int   sxi[64];

  const float* s0 = &sc[(size_t)t * 512];
  for (int i = tid; i < 512; i += 256) {
    unsigned u = f32_ord(s0[i]);
    skey[i] = ((unsigned long long)u << 32) |
              (unsigned)(0xFFFFFFFFu - (unsigned)(i & 255));
  }

  // two independent descending bitonic sorts of 256
  for (int k = 2; k <= 256; k <<= 1)
    for (int j = k >> 1; j > 0; j >>= 1) {
      __syncthreads();
      for (int i = tid; i < 512; i += 256) {
        int ixj = i ^ j;
        if (ixj > i) {
          unsigned long long a = skey[i], b = skey[ixj];
          bool up = (((i & 255) & k) == 0);
          if (up ? (a < b) : (a > b)) { skey[i] = b; skey[ixj] = a; }
        }
      }
    }
  __syncthreads();
  if (tid < 32) {
    unsigned long long ka = skey[tid], kb = skey[256 + tid];
    sxf[tid]      = f32_unord((unsigned)(ka >> 32));
    sxi[tid]      = (int)(0xFFFFFFFFu - (unsigned)(ka & 0xFFFFFFFFu));
    sxf[32 + tid] = f32_unord((unsigned)(kb >> 32));
    sxi[32 + tid] = (int)(0xFFFFFFFFu - (unsigned)(kb & 0xFFFFFFFFu));
  }
  __syncthreads();
  // pair sums in fp32, combo c = i*32 + j
  for (int c = tid; c < 1024; c += 256) {
    float sum = sxf[c >> 5] + sxf[32 + (c & 31)];
    skey[c] = ((unsigned long long)f32_ord(sum) << 32) |
              (unsigned)(0xFFFFFFFFu - (unsigned)c);
  }
  // descending bitonic sort of 1024
  for (int k = 2; k <= 1024; k <<= 1)
    for (int j = k >> 1; j > 0; j >>= 1) {
      __syncthreads();
      for (int i = tid; i < 1024; i += 256) {
        int ixj = i ^ j;
        if (ixj > i) {
          unsigned long long a = skey[i], b = skey[ixj];
          bool up = ((i & k) == 0);
          if (up ? (a < b) : (a > b)) { skey[i] = b; skey[ixj] = a; }
        }
      }
    }
  __syncthreads();
  if (tid < 32) {
    double m0 = (double)f32_unord((unsigned)(skey[0] >> 32));
    unsigned long long kk = skey[tid];
    double v = (double)f32_unord((unsigned)(kk >> 32));
    int c = (int)(0xFFFFFFFFu - (unsigned)(kk & 0xFFFFFFFFu));
    double e = exp(v - m0);
    double ssum = e;
#pragma unroll
    for (int m = 1; m < 32; m <<= 1) ssum += __shfl_xor(ssum, m, 64);
    int vi = sxi[c >> 5] * NKEY + sxi[32 + (c & 31)];
    wout[(size_t)(t * NH + h) * TK + tid] = (float)(e / ssum);
    vout[(size_t)(t * NH + h) * TK + tid] = vi;
  }
}

// ---------------------------------------------------------------------------
// K4: weighted gather: out[t, :] = sum_{j<128} w[t,j] * values[vidx[t,j], :]
// ---------------------------------------------------------------------------
__global__ __launch_bounds__(256) void k_gather(
    const float* __restrict__ values, const float* __restrict__ w,
    const int* __restrict__ vidx, float* __restrict__ out) {
  const int t = blockIdx.x;
  const int tid = threadIdx.x;
  __shared__ float lw[128];
  __shared__ int lv[128];
  if (tid < 128) {
    lw[tid] = w[(size_t)t * 128 + tid];
    lv[tid] = vidx[(size_t)t * 128 + tid];
  }
  __syncthreads();
  float2 acc = make_float2(0.f, 0.f);
#pragma unroll 4
  for (int j = 0; j < 128; ++j) {
    float wj = lw[j];
    const float2 v = *reinterpret_cast<const float2*>(
        &values[(size_t)lv[j] * DIMC + tid * 2]);
    acc.x = fmaf(wj, v.x, acc.x);
    acc.y = fmaf(wj, v.y, acc.y);
  }
  *reinterpret_cast<float2*>(&out[(size_t)t * DIMC + tid * 2]) = acc;
}

// ---------------------------------------------------------------------------
extern "C" void kernel_launch(void* const* d_in, const int* in_sizes, int n_in,
                              void* d_out, int out_size, void* d_ws, size_t ws_size,
                              hipStream_t stream) {
  const float* x      = (const float*)d_in[0];
  const float* wq     = (const float*)d_in[1];
  const float* ln_g   = (const float*)d_in[2];
  const float* ln_b   = (const float*)d_in[3];
  const float* keys   = (const float*)d_in[4];
  const float* values = (const float*)d_in[5];
  float* out = (float*)d_out;

  char* ws = (char*)d_ws;
  float* qn  = (float*)ws;                                  // 4096*1024*4 = 16 MB
  float* sc  = (float*)(ws + 16777216);                     // 4096*512*4  =  8 MB (reused per h)
  float* wv  = (float*)(ws + 16777216 + 8388608);           // 4096*128*4  =  2 MB
  int*   vi  = (int*)(ws + 16777216 + 8388608 + 2097152);   // 4096*128*4  =  2 MB

  k_qproj_ln<<<dim3(64, 8), 256, 0, stream>>>(x, wq, ln_g, ln_b, qn);
  for (int h = 0; h < NH; ++h) {
    k_dots<<<dim3(128, 2), 256, 0, stream>>>(qn, keys, sc, h);
    k_topk<<<dim3(4096), 256, 0, stream>>>(sc, wv, vi, h);
  }
  k_gather<<<dim3(4096), 256, 0, stream>>>(values, wv, vi, out);
}

// Round 5
// 491.217 us; speedup vs baseline: 2.2256x; 2.2256x over previous
//
#include <hip/hip_runtime.h>
#include <hip/hip_bf16.h>

// Problem constants
#define NT    4096   // B*T tokens
#define DIMC  512    // model dim
#define DQ    1024   // DIM_QUERY
#define NH    4      // heads
#define DH    128    // head dim
#define NKEY  256
#define TK    32

typedef unsigned long long u64;
typedef unsigned int u32;

// ---------------------------------------------------------------------------
// K1: Q projection in f32 with sequential FMA chain over c ascending (mirrors
// BLAS/Eigen sgemm microkernel rounding), + fused LayerNorm epilogue.
// ---------------------------------------------------------------------------
__global__ __launch_bounds__(256) void k_qproj_ln(
    const float* __restrict__ x, const float* __restrict__ wq,
    const float* __restrict__ ln_g, const float* __restrict__ ln_b,
    float* __restrict__ qn) {
  const int bm = blockIdx.x * 64;        // token tile
  const int nb = blockIdx.y;             // 0..7 -> 128-dim (p,h) group
  const int n0 = nb * 128;
  const int tid = threadIdx.x;
  const int tx = tid & 15;               // 16 col-groups (8 cols each)
  const int ty = tid >> 4;               // 16 row-groups (4 rows each)

  __shared__ __align__(16) float As[16][68];   // [k][m], padded
  __shared__ __align__(16) float Bs[16][130];  // [k][n], padded

  float acc[4][8];
#pragma unroll
  for (int r = 0; r < 4; ++r)
#pragma unroll
    for (int c = 0; c < 8; ++c) acc[r][c] = 0.0f;

  for (int k0 = 0; k0 < DIMC; k0 += 16) {
    {
      int row = tid >> 2, kg = tid & 3;
      float4 v = *reinterpret_cast<const float4*>(
          &x[(size_t)(bm + row) * DIMC + k0 + kg * 4]);
      As[kg * 4 + 0][row] = v.x; As[kg * 4 + 1][row] = v.y;
      As[kg * 4 + 2][row] = v.z; As[kg * 4 + 3][row] = v.w;
    }
#pragma unroll
    for (int it = 0; it < 2; ++it) {
      int idx = it * 256 + tid;
      int rn = idx >> 2, kg = idx & 3;
      float4 v = *reinterpret_cast<const float4*>(
          &wq[(size_t)(n0 + rn) * DIMC + k0 + kg * 4]);
      Bs[kg * 4 + 0][rn] = v.x; Bs[kg * 4 + 1][rn] = v.y;
      Bs[kg * 4 + 2][rn] = v.z; Bs[kg * 4 + 3][rn] = v.w;
    }
    __syncthreads();
#pragma unroll
    for (int kk = 0; kk < 16; ++kk) {   // k ascending: chain order preserved
      float4 a4 = *reinterpret_cast<const float4*>(&As[kk][ty * 4]);
      float2 bp0 = *reinterpret_cast<const float2*>(&Bs[kk][2 * tx]);
      float2 bp1 = *reinterpret_cast<const float2*>(&Bs[kk][2 * tx + 32]);
      float2 bp2 = *reinterpret_cast<const float2*>(&Bs[kk][2 * tx + 64]);
      float2 bp3 = *reinterpret_cast<const float2*>(&Bs[kk][2 * tx + 96]);
      float af[4] = {a4.x, a4.y, a4.z, a4.w};
      float bf[8] = {bp0.x, bp0.y, bp1.x, bp1.y, bp2.x, bp2.y, bp3.x, bp3.y};
#pragma unroll
      for (int r = 0; r < 4; ++r)
#pragma unroll
        for (int c = 0; c < 8; ++c)
          acc[r][c] = fmaf(af[r], bf[c], acc[r][c]);
    }
    __syncthreads();
  }

  // LayerNorm epilogue (f64 math on the f32 q values; flip-immaterial).
  double gg[8], bb[8];
#pragma unroll
  for (int c = 0; c < 8; ++c) {
    int d = 2 * tx + 32 * (c >> 1) + (c & 1);
    gg[c] = (double)ln_g[d]; bb[c] = (double)ln_b[d];
  }
#pragma unroll
  for (int r = 0; r < 4; ++r) {
    double qf[8];
#pragma unroll
    for (int c = 0; c < 8; ++c) qf[c] = (double)acc[r][c];
    double s = 0.0;
#pragma unroll
    for (int c = 0; c < 8; ++c) s += qf[c];
#pragma unroll
    for (int m = 1; m < 16; m <<= 1) s += __shfl_xor(s, m, 64);
    double mu = s * (1.0 / 128.0);
    double vs = 0.0;
#pragma unroll
    for (int c = 0; c < 8; ++c) { double d = qf[c] - mu; vs += d * d; }
#pragma unroll
    for (int m = 1; m < 16; m <<= 1) vs += __shfl_xor(vs, m, 64);
    double rstd = 1.0 / sqrt(vs * (1.0 / 128.0) + 1e-5);
    float* o = &qn[(size_t)(bm + ty * 4 + r) * DQ + n0];
#pragma unroll
    for (int cp = 0; cp < 4; ++cp) {
      float2 st;
      st.x = (float)((qf[2 * cp] - mu) * rstd * gg[2 * cp] + bb[2 * cp]);
      st.y = (float)((qf[2 * cp + 1] - mu) * rstd * gg[2 * cp + 1] + bb[2 * cp + 1]);
      *reinterpret_cast<float2*>(&o[2 * tx + 32 * cp]) = st;
    }
  }
}

// ---------------------------------------------------------------------------
// K2: dots, all heads in one launch (blockIdx.z = h), f32 sequential FMA.
// sc layout h-major: sc[((h*NT + t)*2 + p)*256 + n]
// ---------------------------------------------------------------------------
__global__ __launch_bounds__(256) void k_dots(
    const float* __restrict__ qn, const float* __restrict__ keys,
    float* __restrict__ sc) {
  const int t0 = blockIdx.x * 32;
  const int p = blockIdx.y;
  const int h = blockIdx.z;
  const int qoff = p * 512 + h * 128;
  const int tid = threadIdx.x;
  const int tx = tid & 31;   // 32 col-groups (8 cols each -> 256)
  const int ty = tid >> 5;   // 8 row-groups (4 rows each -> 32)

  __shared__ __align__(16) float Asf[32][36];   // [k][m] padded
  __shared__ __align__(16) float Bs[32][258];   // [k][n] padded

  float acc[4][8];
#pragma unroll
  for (int r = 0; r < 4; ++r)
#pragma unroll
    for (int c = 0; c < 8; ++c) acc[r][c] = 0.0f;

  for (int k0 = 0; k0 < DH; k0 += 32) {
    {
      int m = tid >> 3, kg = tid & 7;
      float4 v = *reinterpret_cast<const float4*>(
          &qn[(size_t)(t0 + m) * DQ + qoff + k0 + kg * 4]);
      Asf[kg * 4 + 0][m] = v.x; Asf[kg * 4 + 1][m] = v.y;
      Asf[kg * 4 + 2][m] = v.z; Asf[kg * 4 + 3][m] = v.w;
    }
#pragma unroll
    for (int it = 0; it < 8; ++it) {
      int idx = it * 256 + tid;
      int n = idx >> 3, kg = idx & 7;
      float4 v = *reinterpret_cast<const float4*>(
          &keys[(size_t)((h * NKEY + n) * 2 + p) * DH + k0 + kg * 4]);
      Bs[kg * 4 + 0][n] = v.x; Bs[kg * 4 + 1][n] = v.y;
      Bs[kg * 4 + 2][n] = v.z; Bs[kg * 4 + 3][n] = v.w;
    }
    __syncthreads();
#pragma unroll
    for (int kk = 0; kk < 32; ++kk) {   // d ascending
      float4 a4 = *reinterpret_cast<const float4*>(&Asf[kk][ty * 4]);
      float2 b0 = *reinterpret_cast<const float2*>(&Bs[kk][2 * tx]);
      float2 b1 = *reinterpret_cast<const float2*>(&Bs[kk][2 * tx + 64]);
      float2 b2 = *reinterpret_cast<const float2*>(&Bs[kk][2 * tx + 128]);
      float2 b3 = *reinterpret_cast<const float2*>(&Bs[kk][2 * tx + 192]);
      float af[4] = {a4.x, a4.y, a4.z, a4.w};
      float bf[8] = {b0.x, b0.y, b1.x, b1.y, b2.x, b2.y, b3.x, b3.y};
#pragma unroll
      for (int r = 0; r < 4; ++r)
#pragma unroll
        for (int c = 0; c < 8; ++c)
          acc[r][c] = fmaf(af[r], bf[c], acc[r][c]);
    }
    __syncthreads();
  }

#pragma unroll
  for (int r = 0; r < 4; ++r) {
    float* o = &sc[(((size_t)h * NT + (t0 + ty * 4 + r)) * 2 + p) * NKEY];
#pragma unroll
    for (int cp = 0; cp < 4; ++cp) {
      float2 st;
      st.x = acc[r][2 * cp];
      st.y = acc[r][2 * cp + 1];
      *reinterpret_cast<float2*>(&o[2 * tx + 64 * cp]) = st;
    }
  }
}

// ---------------------------------------------------------------------------
// K3: wave-per-(token,head) top-k, zero barriers, zero LDS.
// Keys: (f32_ord(score) << 32) | (0xFFFFFFFF - index) -> desc sort = top-k
// with lax.top_k tie-break (lower index first). fp32 pair sums (monotone,
// bitwise-matching the reference).
// ---------------------------------------------------------------------------
__device__ __forceinline__ u32 ford(float f) {
  u32 u = __float_as_uint(f);
  return u ^ (0x80000000u | (u32)((int)u >> 31));
}
__device__ __forceinline__ float funord(u32 o) {
  u32 b = (o & 0x80000000u) ? (o ^ 0x80000000u) : ~o;
  return __uint_as_float(b);
}

// Candidate down-set {(i,j): (i+1)*(j+1) <= 32}: 119 entries (c = i*32+j),
// padded to 128 with -1.
__device__ const short cand_tbl[128] = {
  // i=0: j=0..31
  0,1,2,3,4,5,6,7,8,9,10,11,12,13,14,15,16,17,18,19,20,21,22,23,24,25,26,27,28,29,30,31,
  // i=1: j=0..15
  32,33,34,35,36,37,38,39,40,41,42,43,44,45,46,47,
  // i=2: j=0..9
  64,65,66,67,68,69,70,71,72,73,
  // i=3: j=0..7
  96,97,98,99,100,101,102,103,
  // i=4: j=0..5
  128,129,130,131,132,133,
  // i=5: j=0..4
  160,161,162,163,164,
  // i=6: j=0..3
  192,193,194,195,
  // i=7: j=0..3
  224,225,226,227,
  // i=8..9: j=0..2
  256,257,258, 288,289,290,
  // i=10..15: j=0..1
  320,321, 352,353, 384,385, 416,417, 448,449, 480,481,
  // i=16..31: j=0
  512,544,576,608,640,672,704,736,768,800,832,864,896,928,960,992,
  // padding
  -1,-1,-1,-1,-1,-1,-1,-1,-1
};

// Descending bitonic sort of 32-element lists (one per half-wave per slot).
template <int NS>
__device__ __forceinline__ void sort32(u64* key, int i) {
#pragma unroll
  for (int k = 2; k <= 32; k <<= 1) {
#pragma unroll
    for (int j = k >> 1; j > 0; j >>= 1) {
      bool up = ((i & k) == 0);
#pragma unroll
      for (int r = 0; r < NS; ++r) {
        u64 o = __shfl_xor(key[r], j, 64);
        u64 mx = key[r] > o ? key[r] : o;
        u64 mn = key[r] < o ? key[r] : o;
        key[r] = (((i & j) == 0) == up) ? mx : mn;
      }
    }
  }
}

// Final 5-step descending bitonic merge of a bitonic 32-seq (per half).
__device__ __forceinline__ u64 bmerge32(u64 a, int i) {
#pragma unroll
  for (int j = 16; j > 0; j >>= 1) {
    u64 o = __shfl_xor(a, j, 64);
    u64 mx = a > o ? a : o;
    u64 mn = a < o ? a : o;
    a = ((i & j) == 0) ? mx : mn;
  }
  return a;
}

// Merge the two desc lists living in the two wave halves of one slot,
// keeping the top-32; result replicated into both halves.
__device__ __forceinline__ u64 mergehalf(u64 a, int i) {
  u64 o = __shfl_xor(a, 63, 64);   // other half, reversed
  a = a > o ? a : o;
  return bmerge32(a, i);
}

// Merge two desc lists in different regs on the same lanes, keep top-32.
__device__ __forceinline__ u64 mergeslots(u64 a, u64 b, int i) {
  u64 o = __shfl_xor(b, 31, 64);   // b reversed within each half
  a = a > o ? a : o;
  return bmerge32(a, i);
}

__global__ __launch_bounds__(256) void k_topk(
    const float* __restrict__ sc, float* __restrict__ wout,
    int* __restrict__ vout) {
  const int t = blockIdx.x;
  const int lane = threadIdx.x & 63;
  const int h = threadIdx.x >> 6;
  const int i = lane & 31;

  // ---- stage 1: top-32 of 256 per p (desc sorted, replicated halves) ----
  u64 X, Y;
#pragma unroll
  for (int p = 0; p < 2; ++p) {
    const float* base = &sc[(((size_t)h * NT + t) * 2 + p) * NKEY];
    u64 key[4];
#pragma unroll
    for (int r = 0; r < 4; ++r) {
      int n = r * 64 + lane;
      key[r] = ((u64)ford(base[n]) << 32) | (u64)(0xFFFFFFFFu - (u32)n);
    }
    sort32<4>(key, i);                       // 8 sorted chunks of 32
#pragma unroll
    for (int r = 0; r < 4; ++r) key[r] = mergehalf(key[r], i);   // -> 4 lists
    u64 m01 = mergeslots(key[0], key[1], i); // -> 2 lists
    u64 m23 = mergeslots(key[2], key[3], i);
    u64 m = mergeslots(m01, m23, i);         // -> top-32 of 256
    if (p == 0) X = m; else Y = m;
  }

  float xs = funord((u32)(X >> 32));         // sx value at rank i (=lane&31)
  float ys = funord((u32)(Y >> 32));
  u32 xn = 0xFFFFFFFFu - (u32)X;             // original key index at rank i
  u32 yn = 0xFFFFFFFFu - (u32)Y;

  // ---- stage 2: top-32 of the 119-candidate down-set of pair sums ----
  u64 s2[2];
#pragma unroll
  for (int r = 0; r < 2; ++r) {
    int ce = (int)cand_tbl[r * 64 + lane];
    int ci = (ce >= 0) ? (ce >> 5) : 0;
    int cj = (ce >= 0) ? (ce & 31) : 0;
    float sum = __shfl(xs, ci, 64) + __shfl(ys, cj, 64);  // fp32, as reference
    u64 kk = ((u64)ford(sum) << 32) | (u64)(0xFFFFFFFFu - (u32)ce);
    s2[r] = (ce >= 0) ? kk : 0ull;
  }
  sort32<2>(s2, i);                          // 4 sorted chunks of 32
#pragma unroll
  for (int r = 0; r < 2; ++r) s2[r] = mergehalf(s2[r], i);
  u64 F = mergeslots(s2[0], s2[1], i);       // top-32 of all pair sums

  // ---- softmax (f64 on the f32 scores) + emit ----
  float fs = funord((u32)(F >> 32));
  u32 c = 0xFFFFFFFFu - (u32)F;
  double m0 = (double)__shfl(fs, 0, 64);
  double e = exp((double)fs - m0);
  double ssum = e;
#pragma unroll
  for (int m = 1; m < 32; m <<= 1) ssum += __shfl_xor(ssum, m, 64);
  int ci = (int)(c >> 5), cj = (int)(c & 31);
  int nx = (int)__shfl(xn, ci, 64);
  int ny = (int)__shfl(yn, cj, 64);
  if (lane < 32) {
    wout[(size_t)(t * NH + h) * TK + lane] = (float)(e / ssum);
    vout[(size_t)(t * NH + h) * TK + lane] = nx * NKEY + ny;
  }
}

// ---------------------------------------------------------------------------
// K4: weighted gather: out[t, :] = sum_{j<128} w[t,j] * values[vidx[t,j], :]
// ---------------------------------------------------------------------------
__global__ __launch_bounds__(256) void k_gather(
    const float* __restrict__ values, const float* __restrict__ w,
    const int* __restrict__ vidx, float* __restrict__ out) {
  const int t = blockIdx.x;
  const int tid = threadIdx.x;
  __shared__ float lw[128];
  __shared__ int lv[128];
  if (tid < 128) {
    lw[tid] = w[(size_t)t * 128 + tid];
    lv[tid] = vidx[(size_t)t * 128 + tid];
  }
  __syncthreads();
  float2 acc = make_float2(0.f, 0.f);
#pragma unroll 4
  for (int j = 0; j < 128; ++j) {
    float wj = lw[j];
    const float2 v = *reinterpret_cast<const float2*>(
        &values[(size_t)lv[j] * DIMC + tid * 2]);
    acc.x = fmaf(wj, v.x, acc.x);
    acc.y = fmaf(wj, v.y, acc.y);
  }
  *reinterpret_cast<float2*>(&out[(size_t)t * DIMC + tid * 2]) = acc;
}

// ---------------------------------------------------------------------------
extern "C" void kernel_launch(void* const* d_in, const int* in_sizes, int n_in,
                              void* d_out, int out_size, void* d_ws, size_t ws_size,
                              hipStream_t stream) {
  const float* x      = (const float*)d_in[0];
  const float* wq     = (const float*)d_in[1];
  const float* ln_g   = (const float*)d_in[2];
  const float* ln_b   = (const float*)d_in[3];
  const float* keys   = (const float*)d_in[4];
  const float* values = (const float*)d_in[5];
  float* out = (float*)d_out;

  char* ws = (char*)d_ws;
  float* qn  = (float*)ws;                                  // 4096*1024*4      = 16 MB
  float* sc  = (float*)(ws + 16777216);                     // 4*4096*512*4     = 32 MB
  float* wv  = (float*)(ws + 16777216 + 33554432);          // 4096*128*4       =  2 MB
  int*   vi  = (int*)(ws + 16777216 + 33554432 + 2097152);  // 4096*128*4       =  2 MB

  k_qproj_ln<<<dim3(64, 8), 256, 0, stream>>>(x, wq, ln_g, ln_b, qn);
  k_dots<<<dim3(128, 2, 4), 256, 0, stream>>>(qn, keys, sc);
  k_topk<<<dim3(4096), 256, 0, stream>>>(sc, wv, vi);
  k_gather<<<dim3(4096), 256, 0, stream>>>(values, wv, vi, out);
}

// Round 6
// 467.950 us; speedup vs baseline: 2.3363x; 1.0497x over previous
//
#include <hip/hip_runtime.h>
#include <hip/hip_bf16.h>

// Problem constants
#define NT    4096   // B*T tokens
#define DIMC  512    // model dim
#define DQ    1024   // DIM_QUERY
#define NH    4      // heads
#define DH    128    // head dim
#define NKEY  256
#define TK    32

typedef unsigned long long u64;
typedef unsigned int u32;

// ---------------------------------------------------------------------------
// K1: Q projection in f32 with sequential FMA chain over c ascending (mirrors
// BLAS/Eigen sgemm microkernel rounding), + fused LayerNorm epilogue.
// ---------------------------------------------------------------------------
__global__ __launch_bounds__(256) void k_qproj_ln(
    const float* __restrict__ x, const float* __restrict__ wq,
    const float* __restrict__ ln_g, const float* __restrict__ ln_b,
    float* __restrict__ qn) {
  const int bm = blockIdx.x * 64;        // token tile
  const int nb = blockIdx.y;             // 0..7 -> 128-dim (p,h) group
  const int n0 = nb * 128;
  const int tid = threadIdx.x;
  const int tx = tid & 15;               // 16 col-groups (8 cols each)
  const int ty = tid >> 4;               // 16 row-groups (4 rows each)

  __shared__ __align__(16) float As[16][68];   // [k][m], padded
  __shared__ __align__(16) float Bs[16][130];  // [k][n], padded

  float acc[4][8];
#pragma unroll
  for (int r = 0; r < 4; ++r)
#pragma unroll
    for (int c = 0; c < 8; ++c) acc[r][c] = 0.0f;

  for (int k0 = 0; k0 < DIMC; k0 += 16) {
    {
      int row = tid >> 2, kg = tid & 3;
      float4 v = *reinterpret_cast<const float4*>(
          &x[(size_t)(bm + row) * DIMC + k0 + kg * 4]);
      As[kg * 4 + 0][row] = v.x; As[kg * 4 + 1][row] = v.y;
      As[kg * 4 + 2][row] = v.z; As[kg * 4 + 3][row] = v.w;
    }
#pragma unroll
    for (int it = 0; it < 2; ++it) {
      int idx = it * 256 + tid;
      int rn = idx >> 2, kg = idx & 3;
      float4 v = *reinterpret_cast<const float4*>(
          &wq[(size_t)(n0 + rn) * DIMC + k0 + kg * 4]);
      Bs[kg * 4 + 0][rn] = v.x; Bs[kg * 4 + 1][rn] = v.y;
      Bs[kg * 4 + 2][rn] = v.z; Bs[kg * 4 + 3][rn] = v.w;
    }
    __syncthreads();
#pragma unroll
    for (int kk = 0; kk < 16; ++kk) {   // k ascending: chain order preserved
      float4 a4 = *reinterpret_cast<const float4*>(&As[kk][ty * 4]);
      float2 bp0 = *reinterpret_cast<const float2*>(&Bs[kk][2 * tx]);
      float2 bp1 = *reinterpret_cast<const float2*>(&Bs[kk][2 * tx + 32]);
      float2 bp2 = *reinterpret_cast<const float2*>(&Bs[kk][2 * tx + 64]);
      float2 bp3 = *reinterpret_cast<const float2*>(&Bs[kk][2 * tx + 96]);
      float af[4] = {a4.x, a4.y, a4.z, a4.w};
      float bf[8] = {bp0.x, bp0.y, bp1.x, bp1.y, bp2.x, bp2.y, bp3.x, bp3.y};
#pragma unroll
      for (int r = 0; r < 4; ++r)
#pragma unroll
        for (int c = 0; c < 8; ++c)
          acc[r][c] = fmaf(af[r], bf[c], acc[r][c]);
    }
    __syncthreads();
  }

  // LayerNorm epilogue (f64 math on the f32 q values; flip-immaterial).
  double gg[8], bb[8];
#pragma unroll
  for (int c = 0; c < 8; ++c) {
    int d = 2 * tx + 32 * (c >> 1) + (c & 1);
    gg[c] = (double)ln_g[d]; bb[c] = (double)ln_b[d];
  }
#pragma unroll
  for (int r = 0; r < 4; ++r) {
    double qf[8];
#pragma unroll
    for (int c = 0; c < 8; ++c) qf[c] = (double)acc[r][c];
    double s = 0.0;
#pragma unroll
    for (int c = 0; c < 8; ++c) s += qf[c];
#pragma unroll
    for (int m = 1; m < 16; m <<= 1) s += __shfl_xor(s, m, 64);
    double mu = s * (1.0 / 128.0);
    double vs = 0.0;
#pragma unroll
    for (int c = 0; c < 8; ++c) { double d = qf[c] - mu; vs += d * d; }
#pragma unroll
    for (int m = 1; m < 16; m <<= 1) vs += __shfl_xor(vs, m, 64);
    double rstd = 1.0 / sqrt(vs * (1.0 / 128.0) + 1e-5);
    float* o = &qn[(size_t)(bm + ty * 4 + r) * DQ + n0];
#pragma unroll
    for (int cp = 0; cp < 4; ++cp) {
      float2 st;
      st.x = (float)((qf[2 * cp] - mu) * rstd * gg[2 * cp] + bb[2 * cp]);
      st.y = (float)((qf[2 * cp + 1] - mu) * rstd * gg[2 * cp + 1] + bb[2 * cp + 1]);
      *reinterpret_cast<float2*>(&o[2 * tx + 32 * cp]) = st;
    }
  }
}

// ---------------------------------------------------------------------------
// K2: dots, all heads in one launch (blockIdx.z = h), f32 sequential FMA.
// sc layout h-major: sc[((h*NT + t)*2 + p)*256 + n]
// ---------------------------------------------------------------------------
__global__ __launch_bounds__(256) void k_dots(
    const float* __restrict__ qn, const float* __restrict__ keys,
    float* __restrict__ sc) {
  const int t0 = blockIdx.x * 32;
  const int p = blockIdx.y;
  const int h = blockIdx.z;
  const int qoff = p * 512 + h * 128;
  const int tid = threadIdx.x;
  const int tx = tid & 31;   // 32 col-groups (8 cols each -> 256)
  const int ty = tid >> 5;   // 8 row-groups (4 rows each -> 32)

  __shared__ __align__(16) float Asf[32][36];   // [k][m] padded
  __shared__ __align__(16) float Bs[32][258];   // [k][n] padded

  float acc[4][8];
#pragma unroll
  for (int r = 0; r < 4; ++r)
#pragma unroll
    for (int c = 0; c < 8; ++c) acc[r][c] = 0.0f;

  for (int k0 = 0; k0 < DH; k0 += 32) {
    {
      int m = tid >> 3, kg = tid & 7;
      float4 v = *reinterpret_cast<const float4*>(
          &qn[(size_t)(t0 + m) * DQ + qoff + k0 + kg * 4]);
      Asf[kg * 4 + 0][m] = v.x; Asf[kg * 4 + 1][m] = v.y;
      Asf[kg * 4 + 2][m] = v.z; Asf[kg * 4 + 3][m] = v.w;
    }
#pragma unroll
    for (int it = 0; it < 8; ++it) {
      int idx = it * 256 + tid;
      int n = idx >> 3, kg = idx & 7;
      float4 v = *reinterpret_cast<const float4*>(
          &keys[(size_t)((h * NKEY + n) * 2 + p) * DH + k0 + kg * 4]);
      Bs[kg * 4 + 0][n] = v.x; Bs[kg * 4 + 1][n] = v.y;
      Bs[kg * 4 + 2][n] = v.z; Bs[kg * 4 + 3][n] = v.w;
    }
    __syncthreads();
#pragma unroll
    for (int kk = 0; kk < 32; ++kk) {   // d ascending
      float4 a4 = *reinterpret_cast<const float4*>(&Asf[kk][ty * 4]);
      float2 b0 = *reinterpret_cast<const float2*>(&Bs[kk][2 * tx]);
      float2 b1 = *reinterpret_cast<const float2*>(&Bs[kk][2 * tx + 64]);
      float2 b2 = *reinterpret_cast<const float2*>(&Bs[kk][2 * tx + 128]);
      float2 b3 = *reinterpret_cast<const float2*>(&Bs[kk][2 * tx + 192]);
      float af[4] = {a4.x, a4.y, a4.z, a4.w};
      float bf[8] = {b0.x, b0.y, b1.x, b1.y, b2.x, b2.y, b3.x, b3.y};
#pragma unroll
      for (int r = 0; r < 4; ++r)
#pragma unroll
        for (int c = 0; c < 8; ++c)
          acc[r][c] = fmaf(af[r], bf[c], acc[r][c]);
    }
    __syncthreads();
  }

#pragma unroll
  for (int r = 0; r < 4; ++r) {
    float* o = &sc[(((size_t)h * NT + (t0 + ty * 4 + r)) * 2 + p) * NKEY];
#pragma unroll
    for (int cp = 0; cp < 4; ++cp) {
      float2 st;
      st.x = acc[r][2 * cp];
      st.y = acc[r][2 * cp + 1];
      *reinterpret_cast<float2*>(&o[2 * tx + 64 * cp]) = st;
    }
  }
}

// ---------------------------------------------------------------------------
// K3: wave-per-(token,head) top-k, zero barriers, zero LDS.
// ---------------------------------------------------------------------------
__device__ __forceinline__ u32 ford(float f) {
  u32 u = __float_as_uint(f);
  return u ^ (0x80000000u | (u32)((int)u >> 31));
}
__device__ __forceinline__ float funord(u32 o) {
  u32 b = (o & 0x80000000u) ? (o ^ 0x80000000u) : ~o;
  return __uint_as_float(b);
}

// Candidate down-set {(i,j): (i+1)*(j+1) <= 32}: 119 entries (c = i*32+j),
// padded to 128 with -1.
__device__ const short cand_tbl[128] = {
  0,1,2,3,4,5,6,7,8,9,10,11,12,13,14,15,16,17,18,19,20,21,22,23,24,25,26,27,28,29,30,31,
  32,33,34,35,36,37,38,39,40,41,42,43,44,45,46,47,
  64,65,66,67,68,69,70,71,72,73,
  96,97,98,99,100,101,102,103,
  128,129,130,131,132,133,
  160,161,162,163,164,
  192,193,194,195,
  224,225,226,227,
  256,257,258, 288,289,290,
  320,321, 352,353, 384,385, 416,417, 448,449, 480,481,
  512,544,576,608,640,672,704,736,768,800,832,864,896,928,960,992,
  -1,-1,-1,-1,-1,-1,-1,-1,-1
};

template <int NS>
__device__ __forceinline__ void sort32(u64* key, int i) {
#pragma unroll
  for (int k = 2; k <= 32; k <<= 1) {
#pragma unroll
    for (int j = k >> 1; j > 0; j >>= 1) {
      bool up = ((i & k) == 0);
#pragma unroll
      for (int r = 0; r < NS; ++r) {
        u64 o = __shfl_xor(key[r], j, 64);
        u64 mx = key[r] > o ? key[r] : o;
        u64 mn = key[r] < o ? key[r] : o;
        key[r] = (((i & j) == 0) == up) ? mx : mn;
      }
    }
  }
}

__device__ __forceinline__ u64 bmerge32(u64 a, int i) {
#pragma unroll
  for (int j = 16; j > 0; j >>= 1) {
    u64 o = __shfl_xor(a, j, 64);
    u64 mx = a > o ? a : o;
    u64 mn = a < o ? a : o;
    a = ((i & j) == 0) ? mx : mn;
  }
  return a;
}

__device__ __forceinline__ u64 mergehalf(u64 a, int i) {
  u64 o = __shfl_xor(a, 63, 64);   // other half, reversed
  a = a > o ? a : o;
  return bmerge32(a, i);
}

__device__ __forceinline__ u64 mergeslots(u64 a, u64 b, int i) {
  u64 o = __shfl_xor(b, 31, 64);   // b reversed within each half
  a = a > o ? a : o;
  return bmerge32(a, i);
}

__global__ __launch_bounds__(256) void k_topk(
    const float* __restrict__ sc, float* __restrict__ wout,
    int* __restrict__ vout) {
  const int t = blockIdx.x;
  const int lane = threadIdx.x & 63;
  const int h = threadIdx.x >> 6;
  const int i = lane & 31;

  u64 X, Y;
#pragma unroll
  for (int p = 0; p < 2; ++p) {
    const float* base = &sc[(((size_t)h * NT + t) * 2 + p) * NKEY];
    u64 key[4];
#pragma unroll
    for (int r = 0; r < 4; ++r) {
      int n = r * 64 + lane;
      key[r] = ((u64)ford(base[n]) << 32) | (u64)(0xFFFFFFFFu - (u32)n);
    }
    sort32<4>(key, i);
#pragma unroll
    for (int r = 0; r < 4; ++r) key[r] = mergehalf(key[r], i);
    u64 m01 = mergeslots(key[0], key[1], i);
    u64 m23 = mergeslots(key[2], key[3], i);
    u64 m = mergeslots(m01, m23, i);
    if (p == 0) X = m; else Y = m;
  }

  float xs = funord((u32)(X >> 32));
  float ys = funord((u32)(Y >> 32));
  u32 xn = 0xFFFFFFFFu - (u32)X;
  u32 yn = 0xFFFFFFFFu - (u32)Y;

  u64 s2[2];
#pragma unroll
  for (int r = 0; r < 2; ++r) {
    int ce = (int)cand_tbl[r * 64 + lane];
    int ci = (ce >= 0) ? (ce >> 5) : 0;
    int cj = (ce >= 0) ? (ce & 31) : 0;
    float sum = __shfl(xs, ci, 64) + __shfl(ys, cj, 64);  // fp32, as reference
    u64 kk = ((u64)ford(sum) << 32) | (u64)(0xFFFFFFFFu - (u32)ce);
    s2[r] = (ce >= 0) ? kk : 0ull;
  }
  sort32<2>(s2, i);
#pragma unroll
  for (int r = 0; r < 2; ++r) s2[r] = mergehalf(s2[r], i);
  u64 F = mergeslots(s2[0], s2[1], i);

  float fs = funord((u32)(F >> 32));
  u32 c = 0xFFFFFFFFu - (u32)F;
  double m0 = (double)__shfl(fs, 0, 64);
  double e = exp((double)fs - m0);
  double ssum = e;
#pragma unroll
  for (int m = 1; m < 32; m <<= 1) ssum += __shfl_xor(ssum, m, 64);
  int ci = (int)(c >> 5), cj = (int)(c & 31);
  int nx = (int)__shfl(xn, ci, 64);
  int ny = (int)__shfl(yn, cj, 64);
  if (lane < 32) {
    wout[(size_t)(t * NH + h) * TK + lane] = (float)(e / ssum);
    vout[(size_t)(t * NH + h) * TK + lane] = nx * NKEY + ny;
  }
}

// ---------------------------------------------------------------------------
// K_cvt: values f32 -> bf16 (RNE), streaming. 65536*512 elems = 8388608
// float4-groups; 4096 blocks x 256 thr x 8 iters.
// ---------------------------------------------------------------------------
__device__ __forceinline__ unsigned short bfr(float f) {
  u32 u = __float_as_uint(f);
  return (unsigned short)((u + 0x7fffu + ((u >> 16) & 1u)) >> 16);
}

__global__ __launch_bounds__(256) void k_cvt(
    const float* __restrict__ v, unsigned short* __restrict__ vb) {
  size_t i = (size_t)blockIdx.x * 256 + threadIdx.x;
  const size_t stride = (size_t)4096 * 256;
#pragma unroll
  for (int it = 0; it < 8; ++it) {
    size_t g = i + (size_t)it * stride;
    float4 a = reinterpret_cast<const float4*>(v)[g];
    ushort4 o;
    o.x = bfr(a.x); o.y = bfr(a.y); o.z = bfr(a.z); o.w = bfr(a.w);
    reinterpret_cast<ushort4*>(vb)[g] = o;
  }
}

// ---------------------------------------------------------------------------
// K4: weighted gather on bf16 values. One block per token; wave w = head w
// owns its 32 rows; lane covers 8 dims via one 16B (8x bf16) load per row.
// LDS 4-way partial reduce at the end.
// ---------------------------------------------------------------------------
__global__ __launch_bounds__(256) void k_gather(
    const unsigned short* __restrict__ vb, const float* __restrict__ w,
    const int* __restrict__ vidx, float* __restrict__ out) {
  const int t = blockIdx.x;
  const int tid = threadIdx.x;
  const int wid = tid >> 6;
  const int lane = tid & 63;
  __shared__ float lw[128];
  __shared__ int lv[128];
  __shared__ float part[4][512];
  if (tid < 128) {
    lw[tid] = w[(size_t)t * 128 + tid];
    lv[tid] = vidx[(size_t)t * 128 + tid];
  }
  __syncthreads();
  float acc[8];
#pragma unroll
  for (int e = 0; e < 8; ++e) acc[e] = 0.f;
  const int jb = wid * 32;
#pragma unroll 8
  for (int k = 0; k < 32; ++k) {
    float wj = lw[jb + k];
    const uint4 v = *reinterpret_cast<const uint4*>(
        &vb[(size_t)lv[jb + k] * DIMC + lane * 8]);
    acc[0] = fmaf(wj, __uint_as_float(v.x << 16), acc[0]);
    acc[1] = fmaf(wj, __uint_as_float(v.x & 0xffff0000u), acc[1]);
    acc[2] = fmaf(wj, __uint_as_float(v.y << 16), acc[2]);
    acc[3] = fmaf(wj, __uint_as_float(v.y & 0xffff0000u), acc[3]);
    acc[4] = fmaf(wj, __uint_as_float(v.z << 16), acc[4]);
    acc[5] = fmaf(wj, __uint_as_float(v.z & 0xffff0000u), acc[5]);
    acc[6] = fmaf(wj, __uint_as_float(v.w << 16), acc[6]);
    acc[7] = fmaf(wj, __uint_as_float(v.w & 0xffff0000u), acc[7]);
  }
  float4* pp = reinterpret_cast<float4*>(&part[wid][lane * 8]);
  pp[0] = make_float4(acc[0], acc[1], acc[2], acc[3]);
  pp[1] = make_float4(acc[4], acc[5], acc[6], acc[7]);
  __syncthreads();
  int d = tid * 2;
  float2 o;
  o.x = (part[0][d]     + part[1][d])     + (part[2][d]     + part[3][d]);
  o.y = (part[0][d + 1] + part[1][d + 1]) + (part[2][d + 1] + part[3][d + 1]);
  *reinterpret_cast<float2*>(&out[(size_t)t * DIMC + d]) = o;
}

// ---------------------------------------------------------------------------
// Workspace layout (68 MB):
//   [0, 64 MB)    vb  (bf16 values)  -- written by k_cvt AFTER qn/sc are dead
//   [0, 16 MB)    qn  (aliases vb; dead after k_dots)
//   [16, 48 MB)   sc  (aliases vb; dead after k_topk)
//   [64, 66 MB)   wv
//   [66, 68 MB)   vi
// ---------------------------------------------------------------------------
extern "C" void kernel_launch(void* const* d_in, const int* in_sizes, int n_in,
                              void* d_out, int out_size, void* d_ws, size_t ws_size,
                              hipStream_t stream) {
  const float* x      = (const float*)d_in[0];
  const float* wq     = (const float*)d_in[1];
  const float* ln_g   = (const float*)d_in[2];
  const float* ln_b   = (const float*)d_in[3];
  const float* keys   = (const float*)d_in[4];
  const float* values = (const float*)d_in[5];
  float* out = (float*)d_out;

  char* ws = (char*)d_ws;
  unsigned short* vb = (unsigned short*)ws;                 // 64 MB
  float* qn  = (float*)ws;                                  // 16 MB (alias)
  float* sc  = (float*)(ws + 16777216);                     // 32 MB (alias)
  float* wv  = (float*)(ws + 67108864);                     //  2 MB
  int*   vi  = (int*)(ws + 67108864 + 2097152);             //  2 MB

  k_qproj_ln<<<dim3(64, 8), 256, 0, stream>>>(x, wq, ln_g, ln_b, qn);
  k_dots<<<dim3(128, 2, 4), 256, 0, stream>>>(qn, keys, sc);
  k_topk<<<dim3(4096), 256, 0, stream>>>(sc, wv, vi);
  k_cvt<<<dim3(4096), 256, 0, stream>>>(values, vb);
  k_gather<<<dim3(4096), 256, 0, stream>>>(vb, wv, vi, out);
}

// Round 7
// 430.308 us; speedup vs baseline: 2.5407x; 1.0875x over previous
//
#include <hip/hip_runtime.h>
#include <hip/hip_bf16.h>

// Problem constants
#define NT    4096   // B*T tokens
#define DIMC  512    // model dim
#define DQ    1024   // DIM_QUERY
#define NH    4      // heads
#define DH    128    // head dim
#define NKEY  256
#define TK    32

typedef unsigned long long u64;
typedef unsigned int u32;

__device__ __forceinline__ unsigned short bfr(float f) {
  u32 u = __float_as_uint(f);
  return (unsigned short)((u + 0x7fffu + ((u >> 16) & 1u)) >> 16);
}

// ---------------------------------------------------------------------------
// K1 (fused): blocks [0,256) = Q projection 128x128 tile + LN epilogue;
// blocks [256, 256+nCvt) = values f32->bf16 streaming convert.
// Per-output FMA chain: single accumulator, k ascending (bitwise == R6).
// ---------------------------------------------------------------------------
__global__ __launch_bounds__(256) void k_qproj_cvt(
    const float* __restrict__ x, const float* __restrict__ wq,
    const float* __restrict__ ln_g, const float* __restrict__ ln_b,
    float* __restrict__ qn, const float* __restrict__ vals,
    unsigned short* __restrict__ vb, int nCvt) {
  const int tid = threadIdx.x;

  if (blockIdx.x >= 256) {
    // ---- cvt part: 8,388,608 float4-groups over nCvt*256 threads ----
    const size_t nthr = (size_t)nCvt * 256;
    size_t g0 = (size_t)(blockIdx.x - 256) * 256 + tid;
    for (size_t g = g0; g < 8388608ull; g += nthr) {
      float4 a = reinterpret_cast<const float4*>(vals)[g];
      ushort4 o;
      o.x = bfr(a.x); o.y = bfr(a.y); o.z = bfr(a.z); o.w = bfr(a.w);
      reinterpret_cast<ushort4*>(vb)[g] = o;
    }
    return;
  }

  // ---- qproj part: tile 128 tokens x 128 qdims ----
  const int bm = (blockIdx.x & 31) * 128;   // token tile
  const int n0 = (blockIdx.x >> 5) * 128;   // (p,h) 128-dim group
  const int tx = tid & 15;                  // 16 col-groups (8 cols each)
  const int ty = tid >> 4;                  // 16 row-groups (8 rows each)

  __shared__ __align__(16) float As[16][132];  // [k][m], padded
  __shared__ __align__(16) float Bs[16][130];  // [k][n], padded

  float acc[8][8];
#pragma unroll
  for (int r = 0; r < 8; ++r)
#pragma unroll
    for (int c = 0; c < 8; ++c) acc[r][c] = 0.0f;

  for (int k0 = 0; k0 < DIMC; k0 += 16) {
#pragma unroll
    for (int it = 0; it < 2; ++it) {     // stage A: 128 rows x 16 k
      int idx = it * 256 + tid;
      int row = idx >> 2, kg = idx & 3;
      float4 v = *reinterpret_cast<const float4*>(
          &x[(size_t)(bm + row) * DIMC + k0 + kg * 4]);
      As[kg * 4 + 0][row] = v.x; As[kg * 4 + 1][row] = v.y;
      As[kg * 4 + 2][row] = v.z; As[kg * 4 + 3][row] = v.w;
    }
#pragma unroll
    for (int it = 0; it < 2; ++it) {     // stage B: 128 n-rows x 16 k
      int idx = it * 256 + tid;
      int rn = idx >> 2, kg = idx & 3;
      float4 v = *reinterpret_cast<const float4*>(
          &wq[(size_t)(n0 + rn) * DIMC + k0 + kg * 4]);
      Bs[kg * 4 + 0][rn] = v.x; Bs[kg * 4 + 1][rn] = v.y;
      Bs[kg * 4 + 2][rn] = v.z; Bs[kg * 4 + 3][rn] = v.w;
    }
    __syncthreads();
#pragma unroll
    for (int kk = 0; kk < 16; ++kk) {    // k ascending
      float4 alo = *reinterpret_cast<const float4*>(&As[kk][ty * 8]);
      float4 ahi = *reinterpret_cast<const float4*>(&As[kk][ty * 8 + 4]);
      float2 bp0 = *reinterpret_cast<const float2*>(&Bs[kk][2 * tx]);
      float2 bp1 = *reinterpret_cast<const float2*>(&Bs[kk][2 * tx + 32]);
      float2 bp2 = *reinterpret_cast<const float2*>(&Bs[kk][2 * tx + 64]);
      float2 bp3 = *reinterpret_cast<const float2*>(&Bs[kk][2 * tx + 96]);
      float af[8] = {alo.x, alo.y, alo.z, alo.w, ahi.x, ahi.y, ahi.z, ahi.w};
      float bf[8] = {bp0.x, bp0.y, bp1.x, bp1.y, bp2.x, bp2.y, bp3.x, bp3.y};
#pragma unroll
      for (int r = 0; r < 8; ++r)
#pragma unroll
        for (int c = 0; c < 8; ++c)
          acc[r][c] = fmaf(af[r], bf[c], acc[r][c]);
    }
    __syncthreads();
  }

  // LayerNorm epilogue (f64 math on the f32 q values; flip-immaterial).
  double gg[8], bb[8];
#pragma unroll
  for (int c = 0; c < 8; ++c) {
    int d = 2 * tx + 32 * (c >> 1) + (c & 1);
    gg[c] = (double)ln_g[d]; bb[c] = (double)ln_b[d];
  }
#pragma unroll
  for (int r = 0; r < 8; ++r) {
    double qf[8];
#pragma unroll
    for (int c = 0; c < 8; ++c) qf[c] = (double)acc[r][c];
    double s = 0.0;
#pragma unroll
    for (int c = 0; c < 8; ++c) s += qf[c];
#pragma unroll
    for (int m = 1; m < 16; m <<= 1) s += __shfl_xor(s, m, 64);
    double mu = s * (1.0 / 128.0);
    double vs = 0.0;
#pragma unroll
    for (int c = 0; c < 8; ++c) { double d = qf[c] - mu; vs += d * d; }
#pragma unroll
    for (int m = 1; m < 16; m <<= 1) vs += __shfl_xor(vs, m, 64);
    double rstd = 1.0 / sqrt(vs * (1.0 / 128.0) + 1e-5);
    float* o = &qn[(size_t)(bm + ty * 8 + r) * DQ + n0];
#pragma unroll
    for (int cp = 0; cp < 4; ++cp) {
      float2 st;
      st.x = (float)((qf[2 * cp] - mu) * rstd * gg[2 * cp] + bb[2 * cp]);
      st.y = (float)((qf[2 * cp + 1] - mu) * rstd * gg[2 * cp + 1] + bb[2 * cp + 1]);
      *reinterpret_cast<float2*>(&o[2 * tx + 32 * cp]) = st;
    }
  }
}

// ---------------------------------------------------------------------------
// K2: dots, tile 64 tokens x 256 keys, 8x8 per thread, f32 sequential FMA.
// sc layout h-major: sc[((h*NT + t)*2 + p)*256 + n]
// ---------------------------------------------------------------------------
__global__ __launch_bounds__(256) void k_dots(
    const float* __restrict__ qn, const float* __restrict__ keys,
    float* __restrict__ sc) {
  const int t0 = blockIdx.x * 64;
  const int p = blockIdx.y;
  const int h = blockIdx.z;
  const int qoff = p * 512 + h * 128;
  const int tid = threadIdx.x;
  const int tx = tid & 31;   // 32 col-groups (8 cols each -> 256)
  const int ty = tid >> 5;   // 8 row-groups (8 rows each -> 64)

  __shared__ __align__(16) float Asf[32][68];   // [k][m] padded
  __shared__ __align__(16) float Bs[32][258];   // [k][n] padded

  float acc[8][8];
#pragma unroll
  for (int r = 0; r < 8; ++r)
#pragma unroll
    for (int c = 0; c < 8; ++c) acc[r][c] = 0.0f;

  for (int k0 = 0; k0 < DH; k0 += 32) {
#pragma unroll
    for (int it = 0; it < 2; ++it) {    // stage A: 64 rows x 32 k
      int idx = it * 256 + tid;
      int m = idx >> 3, kg = idx & 7;
      float4 v = *reinterpret_cast<const float4*>(
          &qn[(size_t)(t0 + m) * DQ + qoff + k0 + kg * 4]);
      Asf[kg * 4 + 0][m] = v.x; Asf[kg * 4 + 1][m] = v.y;
      Asf[kg * 4 + 2][m] = v.z; Asf[kg * 4 + 3][m] = v.w;
    }
#pragma unroll
    for (int it = 0; it < 8; ++it) {    // stage B: 256 keys x 32 k
      int idx = it * 256 + tid;
      int n = idx >> 3, kg = idx & 7;
      float4 v = *reinterpret_cast<const float4*>(
          &keys[(size_t)((h * NKEY + n) * 2 + p) * DH + k0 + kg * 4]);
      Bs[kg * 4 + 0][n] = v.x; Bs[kg * 4 + 1][n] = v.y;
      Bs[kg * 4 + 2][n] = v.z; Bs[kg * 4 + 3][n] = v.w;
    }
    __syncthreads();
#pragma unroll
    for (int kk = 0; kk < 32; ++kk) {   // d ascending
      float4 alo = *reinterpret_cast<const float4*>(&Asf[kk][ty * 8]);
      float4 ahi = *reinterpret_cast<const float4*>(&Asf[kk][ty * 8 + 4]);
      float2 b0 = *reinterpret_cast<const float2*>(&Bs[kk][2 * tx]);
      float2 b1 = *reinterpret_cast<const float2*>(&Bs[kk][2 * tx + 64]);
      float2 b2 = *reinterpret_cast<const float2*>(&Bs[kk][2 * tx + 128]);
      float2 b3 = *reinterpret_cast<const float2*>(&Bs[kk][2 * tx + 192]);
      float af[8] = {alo.x, alo.y, alo.z, alo.w, ahi.x, ahi.y, ahi.z, ahi.w};
      float bf[8] = {b0.x, b0.y, b1.x, b1.y, b2.x, b2.y, b3.x, b3.y};
#pragma unroll
      for (int r = 0; r < 8; ++r)
#pragma unroll
        for (int c = 0; c < 8; ++c)
          acc[r][c] = fmaf(af[r], bf[c], acc[r][c]);
    }
    __syncthreads();
  }

#pragma unroll
  for (int r = 0; r < 8; ++r) {
    float* o = &sc[(((size_t)h * NT + (t0 + ty * 8 + r)) * 2 + p) * NKEY];
#pragma unroll
    for (int cp = 0; cp < 4; ++cp) {
      float2 st;
      st.x = acc[r][2 * cp];
      st.y = acc[r][2 * cp + 1];
      *reinterpret_cast<float2*>(&o[2 * tx + 64 * cp]) = st;
    }
  }
}

// ---------------------------------------------------------------------------
// K3: wave-per-(token,head) top-k, zero barriers, zero LDS. (unchanged)
// ---------------------------------------------------------------------------
__device__ __forceinline__ u32 ford(float f) {
  u32 u = __float_as_uint(f);
  return u ^ (0x80000000u | (u32)((int)u >> 31));
}
__device__ __forceinline__ float funord(u32 o) {
  u32 b = (o & 0x80000000u) ? (o ^ 0x80000000u) : ~o;
  return __uint_as_float(b);
}

// Candidate down-set {(i,j): (i+1)*(j+1) <= 32}: 119 entries (c = i*32+j),
// padded to 128 with -1.
__device__ const short cand_tbl[128] = {
  0,1,2,3,4,5,6,7,8,9,10,11,12,13,14,15,16,17,18,19,20,21,22,23,24,25,26,27,28,29,30,31,
  32,33,34,35,36,37,38,39,40,41,42,43,44,45,46,47,
  64,65,66,67,68,69,70,71,72,73,
  96,97,98,99,100,101,102,103,
  128,129,130,131,132,133,
  160,161,162,163,164,
  192,193,194,195,
  224,225,226,227,
  256,257,258, 288,289,290,
  320,321, 352,353, 384,385, 416,417, 448,449, 480,481,
  512,544,576,608,640,672,704,736,768,800,832,864,896,928,960,992,
  -1,-1,-1,-1,-1,-1,-1,-1,-1
};

template <int NS>
__device__ __forceinline__ void sort32(u64* key, int i) {
#pragma unroll
  for (int k = 2; k <= 32; k <<= 1) {
#pragma unroll
    for (int j = k >> 1; j > 0; j >>= 1) {
      bool up = ((i & k) == 0);
#pragma unroll
      for (int r = 0; r < NS; ++r) {
        u64 o = __shfl_xor(key[r], j, 64);
        u64 mx = key[r] > o ? key[r] : o;
        u64 mn = key[r] < o ? key[r] : o;
        key[r] = (((i & j) == 0) == up) ? mx : mn;
      }
    }
  }
}

__device__ __forceinline__ u64 bmerge32(u64 a, int i) {
#pragma unroll
  for (int j = 16; j > 0; j >>= 1) {
    u64 o = __shfl_xor(a, j, 64);
    u64 mx = a > o ? a : o;
    u64 mn = a < o ? a : o;
    a = ((i & j) == 0) ? mx : mn;
  }
  return a;
}

__device__ __forceinline__ u64 mergehalf(u64 a, int i) {
  u64 o = __shfl_xor(a, 63, 64);   // other half, reversed
  a = a > o ? a : o;
  return bmerge32(a, i);
}

__device__ __forceinline__ u64 mergeslots(u64 a, u64 b, int i) {
  u64 o = __shfl_xor(b, 31, 64);   // b reversed within each half
  a = a > o ? a : o;
  return bmerge32(a, i);
}

__global__ __launch_bounds__(256) void k_topk(
    const float* __restrict__ sc, float* __restrict__ wout,
    int* __restrict__ vout) {
  const int t = blockIdx.x;
  const int lane = threadIdx.x & 63;
  const int h = threadIdx.x >> 6;
  const int i = lane & 31;

  u64 X, Y;
#pragma unroll
  for (int p = 0; p < 2; ++p) {
    const float* base = &sc[(((size_t)h * NT + t) * 2 + p) * NKEY];
    u64 key[4];
#pragma unroll
    for (int r = 0; r < 4; ++r) {
      int n = r * 64 + lane;
      key[r] = ((u64)ford(base[n]) << 32) | (u64)(0xFFFFFFFFu - (u32)n);
    }
    sort32<4>(key, i);
#pragma unroll
    for (int r = 0; r < 4; ++r) key[r] = mergehalf(key[r], i);
    u64 m01 = mergeslots(key[0], key[1], i);
    u64 m23 = mergeslots(key[2], key[3], i);
    u64 m = mergeslots(m01, m23, i);
    if (p == 0) X = m; else Y = m;
  }

  float xs = funord((u32)(X >> 32));
  float ys = funord((u32)(Y >> 32));
  u32 xn = 0xFFFFFFFFu - (u32)X;
  u32 yn = 0xFFFFFFFFu - (u32)Y;

  u64 s2[2];
#pragma unroll
  for (int r = 0; r < 2; ++r) {
    int ce = (int)cand_tbl[r * 64 + lane];
    int ci = (ce >= 0) ? (ce >> 5) : 0;
    int cj = (ce >= 0) ? (ce & 31) : 0;
    float sum = __shfl(xs, ci, 64) + __shfl(ys, cj, 64);  // fp32, as reference
    u64 kk = ((u64)ford(sum) << 32) | (u64)(0xFFFFFFFFu - (u32)ce);
    s2[r] = (ce >= 0) ? kk : 0ull;
  }
  sort32<2>(s2, i);
#pragma unroll
  for (int r = 0; r < 2; ++r) s2[r] = mergehalf(s2[r], i);
  u64 F = mergeslots(s2[0], s2[1], i);

  float fs = funord((u32)(F >> 32));
  u32 c = 0xFFFFFFFFu - (u32)F;
  double m0 = (double)__shfl(fs, 0, 64);
  double e = exp((double)fs - m0);
  double ssum = e;
#pragma unroll
  for (int m = 1; m < 32; m <<= 1) ssum += __shfl_xor(ssum, m, 64);
  int ci = (int)(c >> 5), cj = (int)(c & 31);
  int nx = (int)__shfl(xn, ci, 64);
  int ny = (int)__shfl(yn, cj, 64);
  if (lane < 32) {
    wout[(size_t)(t * NH + h) * TK + lane] = (float)(e / ssum);
    vout[(size_t)(t * NH + h) * TK + lane] = nx * NKEY + ny;
  }
}

// ---------------------------------------------------------------------------
// K_cvt (fallback mode only): values f32 -> bf16 streaming.
// ---------------------------------------------------------------------------
__global__ __launch_bounds__(256) void k_cvt(
    const float* __restrict__ v, unsigned short* __restrict__ vb) {
  size_t i = (size_t)blockIdx.x * 256 + threadIdx.x;
  const size_t stride = (size_t)4096 * 256;
#pragma unroll
  for (int it = 0; it < 8; ++it) {
    size_t g = i + (size_t)it * stride;
    float4 a = reinterpret_cast<const float4*>(v)[g];
    ushort4 o;
    o.x = bfr(a.x); o.y = bfr(a.y); o.z = bfr(a.z); o.w = bfr(a.w);
    reinterpret_cast<ushort4*>(vb)[g] = o;
  }
}

// ---------------------------------------------------------------------------
// K4: weighted gather on bf16 values. (unchanged)
// ---------------------------------------------------------------------------
__global__ __launch_bounds__(256) void k_gather(
    const unsigned short* __restrict__ vb, const float* __restrict__ w,
    const int* __restrict__ vidx, float* __restrict__ out) {
  const int t = blockIdx.x;
  const int tid = threadIdx.x;
  const int wid = tid >> 6;
  const int lane = tid & 63;
  __shared__ float lw[128];
  __shared__ int lv[128];
  __shared__ float part[4][512];
  if (tid < 128) {
    lw[tid] = w[(size_t)t * 128 + tid];
    lv[tid] = vidx[(size_t)t * 128 + tid];
  }
  __syncthreads();
  float acc[8];
#pragma unroll
  for (int e = 0; e < 8; ++e) acc[e] = 0.f;
  const int jb = wid * 32;
#pragma unroll 8
  for (int k = 0; k < 32; ++k) {
    float wj = lw[jb + k];
    const uint4 v = *reinterpret_cast<const uint4*>(
        &vb[(size_t)lv[jb + k] * DIMC + lane * 8]);
    acc[0] = fmaf(wj, __uint_as_float(v.x << 16), acc[0]);
    acc[1] = fmaf(wj, __uint_as_float(v.x & 0xffff0000u), acc[1]);
    acc[2] = fmaf(wj, __uint_as_float(v.y << 16), acc[2]);
    acc[3] = fmaf(wj, __uint_as_float(v.y & 0xffff0000u), acc[3]);
    acc[4] = fmaf(wj, __uint_as_float(v.z << 16), acc[4]);
    acc[5] = fmaf(wj, __uint_as_float(v.z & 0xffff0000u), acc[5]);
    acc[6] = fmaf(wj, __uint_as_float(v.w << 16), acc[6]);
    acc[7] = fmaf(wj, __uint_as_float(v.w & 0xffff0000u), acc[7]);
  }
  float4* pp = reinterpret_cast<float4*>(&part[wid][lane * 8]);
  pp[0] = make_float4(acc[0], acc[1], acc[2], acc[3]);
  pp[1] = make_float4(acc[4], acc[5], acc[6], acc[7]);
  __syncthreads();
  int d = tid * 2;
  float2 o;
  o.x = (part[0][d]     + part[1][d])     + (part[2][d]     + part[3][d]);
  o.y = (part[0][d + 1] + part[1][d + 1]) + (part[2][d + 1] + part[3][d + 1]);
  *reinterpret_cast<float2*>(&out[(size_t)t * DIMC + d]) = o;
}

// ---------------------------------------------------------------------------
// Workspace:
//  overlap mode (ws >= 116 MB): qn[0,16) sc[16,48) vb[48,112) wv[112,114) vi[114,116)
//    k_qproj_cvt(256+1024 blocks) -> k_dots -> k_topk -> k_gather
//  fallback (ws >= 68 MB): vb[0,64) aliases qn[0,16)+sc[16,48); wv[64,66) vi[66,68)
//    k_qproj_cvt(256 blocks, nCvt=0) -> k_dots -> k_topk -> k_cvt -> k_gather
// Branch depends only on ws_size (launch-constant): graph-safe.
// ---------------------------------------------------------------------------
extern "C" void kernel_launch(void* const* d_in, const int* in_sizes, int n_in,
                              void* d_out, int out_size, void* d_ws, size_t ws_size,
                              hipStream_t stream) {
  const float* x      = (const float*)d_in[0];
  const float* wq     = (const float*)d_in[1];
  const float* ln_g   = (const float*)d_in[2];
  const float* ln_b   = (const float*)d_in[3];
  const float* keys   = (const float*)d_in[4];
  const float* values = (const float*)d_in[5];
  float* out = (float*)d_out;

  char* ws = (char*)d_ws;
  const bool overlap = ws_size >= (size_t)116 * 1024 * 1024;

  float* qn = (float*)ws;                         // 16 MB
  float* sc = (float*)(ws + (16ull << 20));       // 32 MB
  unsigned short* vb;
  float* wv;
  int*   vi;
  if (overlap) {
    vb = (unsigned short*)(ws + (48ull << 20));   // 64 MB
    wv = (float*)(ws + (112ull << 20));
    vi = (int*)(ws + (114ull << 20));
  } else {
    vb = (unsigned short*)ws;                     // aliases qn+sc (written late)
    wv = (float*)(ws + (64ull << 20));
    vi = (int*)(ws + (66ull << 20));
  }

  const int nCvt = overlap ? 1024 : 0;
  k_qproj_cvt<<<dim3(256 + nCvt), 256, 0, stream>>>(
      x, wq, ln_g, ln_b, qn, values, vb, nCvt);
  k_dots<<<dim3(64, 2, 4), 256, 0, stream>>>(qn, keys, sc);
  k_topk<<<dim3(4096), 256, 0, stream>>>(sc, wv, vi);
  if (!overlap) k_cvt<<<dim3(4096), 256, 0, stream>>>(values, vb);
  k_gather<<<dim3(4096), 256, 0, stream>>>(vb, wv, vi, out);
}

// Round 8
// 420.015 us; speedup vs baseline: 2.6029x; 1.0245x over previous
//
#include <hip/hip_runtime.h>
#include <hip/hip_bf16.h>

// Problem constants
#define NT    4096   // B*T tokens
#define DIMC  512    // model dim
#define DQ    1024   // DIM_QUERY
#define NH    4      // heads
#define DH    128    // head dim
#define NKEY  256
#define TK    32

typedef unsigned long long u64;
typedef unsigned int u32;

__device__ __forceinline__ unsigned short bfr(float f) {
  u32 u = __float_as_uint(f);
  return (unsigned short)((u + 0x7fffu + ((u >> 16) & 1u)) >> 16);
}

// ---------------------------------------------------------------------------
// K1 (fused): blocks [0,512) = Q projection 64x128 tile + LN epilogue
// (2 blocks/CU -> 8 waves/CU); blocks [512, 512+nCvt) = values f32->bf16.
// Per-output FMA chain: single accumulator, k ascending (bitwise == R6).
// ---------------------------------------------------------------------------
__global__ __launch_bounds__(256) void k_qproj_cvt(
    const float* __restrict__ x, const float* __restrict__ wq,
    const float* __restrict__ ln_g, const float* __restrict__ ln_b,
    float* __restrict__ qn, const float* __restrict__ vals,
    unsigned short* __restrict__ vb, int nCvt) {
  const int tid = threadIdx.x;

  if (blockIdx.x >= 512) {
    // ---- cvt part: 8,388,608 float4-groups over nCvt*256 threads ----
    const size_t nthr = (size_t)nCvt * 256;
    size_t g0 = (size_t)(blockIdx.x - 512) * 256 + tid;
    for (size_t g = g0; g < 8388608ull; g += nthr) {
      float4 a = reinterpret_cast<const float4*>(vals)[g];
      ushort4 o;
      o.x = bfr(a.x); o.y = bfr(a.y); o.z = bfr(a.z); o.w = bfr(a.w);
      reinterpret_cast<ushort4*>(vb)[g] = o;
    }
    return;
  }

  // ---- qproj part: tile 64 tokens x 128 qdims ----
  const int bm = (blockIdx.x & 63) * 64;    // token tile
  const int n0 = (blockIdx.x >> 6) * 128;   // (p,h) 128-dim group
  const int tx = tid & 15;                  // 16 col-groups (8 cols each)
  const int ty = tid >> 4;                  // 16 row-groups (4 rows each)

  __shared__ __align__(16) float As[16][68];   // [k][m], padded
  __shared__ __align__(16) float Bs[16][130];  // [k][n], padded

  float acc[4][8];
#pragma unroll
  for (int r = 0; r < 4; ++r)
#pragma unroll
    for (int c = 0; c < 8; ++c) acc[r][c] = 0.0f;

  for (int k0 = 0; k0 < DIMC; k0 += 16) {
    {
      int row = tid >> 2, kg = tid & 3;
      float4 v = *reinterpret_cast<const float4*>(
          &x[(size_t)(bm + row) * DIMC + k0 + kg * 4]);
      As[kg * 4 + 0][row] = v.x; As[kg * 4 + 1][row] = v.y;
      As[kg * 4 + 2][row] = v.z; As[kg * 4 + 3][row] = v.w;
    }
#pragma unroll
    for (int it = 0; it < 2; ++it) {
      int idx = it * 256 + tid;
      int rn = idx >> 2, kg = idx & 3;
      float4 v = *reinterpret_cast<const float4*>(
          &wq[(size_t)(n0 + rn) * DIMC + k0 + kg * 4]);
      Bs[kg * 4 + 0][rn] = v.x; Bs[kg * 4 + 1][rn] = v.y;
      Bs[kg * 4 + 2][rn] = v.z; Bs[kg * 4 + 3][rn] = v.w;
    }
    __syncthreads();
#pragma unroll
    for (int kk = 0; kk < 16; ++kk) {   // k ascending: chain order preserved
      float4 a4 = *reinterpret_cast<const float4*>(&As[kk][ty * 4]);
      float2 bp0 = *reinterpret_cast<const float2*>(&Bs[kk][2 * tx]);
      float2 bp1 = *reinterpret_cast<const float2*>(&Bs[kk][2 * tx + 32]);
      float2 bp2 = *reinterpret_cast<const float2*>(&Bs[kk][2 * tx + 64]);
      float2 bp3 = *reinterpret_cast<const float2*>(&Bs[kk][2 * tx + 96]);
      float af[4] = {a4.x, a4.y, a4.z, a4.w};
      float bf[8] = {bp0.x, bp0.y, bp1.x, bp1.y, bp2.x, bp2.y, bp3.x, bp3.y};
#pragma unroll
      for (int r = 0; r < 4; ++r)
#pragma unroll
        for (int c = 0; c < 8; ++c)
          acc[r][c] = fmaf(af[r], bf[c], acc[r][c]);
    }
    __syncthreads();
  }

  // LayerNorm epilogue (f64 math on the f32 q values; flip-immaterial).
  double gg[8], bb[8];
#pragma unroll
  for (int c = 0; c < 8; ++c) {
    int d = 2 * tx + 32 * (c >> 1) + (c & 1);
    gg[c] = (double)ln_g[d]; bb[c] = (double)ln_b[d];
  }
#pragma unroll
  for (int r = 0; r < 4; ++r) {
    double qf[8];
#pragma unroll
    for (int c = 0; c < 8; ++c) qf[c] = (double)acc[r][c];
    double s = 0.0;
#pragma unroll
    for (int c = 0; c < 8; ++c) s += qf[c];
#pragma unroll
    for (int m = 1; m < 16; m <<= 1) s += __shfl_xor(s, m, 64);
    double mu = s * (1.0 / 128.0);
    double vs = 0.0;
#pragma unroll
    for (int c = 0; c < 8; ++c) { double d = qf[c] - mu; vs += d * d; }
#pragma unroll
    for (int m = 1; m < 16; m <<= 1) vs += __shfl_xor(vs, m, 64);
    double rstd = 1.0 / sqrt(vs * (1.0 / 128.0) + 1e-5);
    float* o = &qn[(size_t)(bm + ty * 4 + r) * DQ + n0];
#pragma unroll
    for (int cp = 0; cp < 4; ++cp) {
      float2 st;
      st.x = (float)((qf[2 * cp] - mu) * rstd * gg[2 * cp] + bb[2 * cp]);
      st.y = (float)((qf[2 * cp + 1] - mu) * rstd * gg[2 * cp + 1] + bb[2 * cp + 1]);
      *reinterpret_cast<float2*>(&o[2 * tx + 32 * cp]) = st;
    }
  }
}

// ---------------------------------------------------------------------------
// K2: dots, tile 64 tokens x 256 keys, 8x8 per thread, f32 sequential FMA.
// sc layout h-major: sc[((h*NT + t)*2 + p)*256 + n]
// ---------------------------------------------------------------------------
__global__ __launch_bounds__(256) void k_dots(
    const float* __restrict__ qn, const float* __restrict__ keys,
    float* __restrict__ sc) {
  const int t0 = blockIdx.x * 64;
  const int p = blockIdx.y;
  const int h = blockIdx.z;
  const int qoff = p * 512 + h * 128;
  const int tid = threadIdx.x;
  const int tx = tid & 31;   // 32 col-groups (8 cols each -> 256)
  const int ty = tid >> 5;   // 8 row-groups (8 rows each -> 64)

  __shared__ __align__(16) float Asf[32][68];   // [k][m] padded
  __shared__ __align__(16) float Bs[32][258];   // [k][n] padded

  float acc[8][8];
#pragma unroll
  for (int r = 0; r < 8; ++r)
#pragma unroll
    for (int c = 0; c < 8; ++c) acc[r][c] = 0.0f;

  for (int k0 = 0; k0 < DH; k0 += 32) {
#pragma unroll
    for (int it = 0; it < 2; ++it) {    // stage A: 64 rows x 32 k
      int idx = it * 256 + tid;
      int m = idx >> 3, kg = idx & 7;
      float4 v = *reinterpret_cast<const float4*>(
          &qn[(size_t)(t0 + m) * DQ + qoff + k0 + kg * 4]);
      Asf[kg * 4 + 0][m] = v.x; Asf[kg * 4 + 1][m] = v.y;
      Asf[kg * 4 + 2][m] = v.z; Asf[kg * 4 + 3][m] = v.w;
    }
#pragma unroll
    for (int it = 0; it < 8; ++it) {    // stage B: 256 keys x 32 k
      int idx = it * 256 + tid;
      int n = idx >> 3, kg = idx & 7;
      float4 v = *reinterpret_cast<const float4*>(
          &keys[(size_t)((h * NKEY + n) * 2 + p) * DH + k0 + kg * 4]);
      Bs[kg * 4 + 0][n] = v.x; Bs[kg * 4 + 1][n] = v.y;
      Bs[kg * 4 + 2][n] = v.z; Bs[kg * 4 + 3][n] = v.w;
    }
    __syncthreads();
#pragma unroll
    for (int kk = 0; kk < 32; ++kk) {   // d ascending
      float4 alo = *reinterpret_cast<const float4*>(&Asf[kk][ty * 8]);
      float4 ahi = *reinterpret_cast<const float4*>(&Asf[kk][ty * 8 + 4]);
      float2 b0 = *reinterpret_cast<const float2*>(&Bs[kk][2 * tx]);
      float2 b1 = *reinterpret_cast<const float2*>(&Bs[kk][2 * tx + 64]);
      float2 b2 = *reinterpret_cast<const float2*>(&Bs[kk][2 * tx + 128]);
      float2 b3 = *reinterpret_cast<const float2*>(&Bs[kk][2 * tx + 192]);
      float af[8] = {alo.x, alo.y, alo.z, alo.w, ahi.x, ahi.y, ahi.z, ahi.w};
      float bf[8] = {b0.x, b0.y, b1.x, b1.y, b2.x, b2.y, b3.x, b3.y};
#pragma unroll
      for (int r = 0; r < 8; ++r)
#pragma unroll
        for (int c = 0; c < 8; ++c)
          acc[r][c] = fmaf(af[r], bf[c], acc[r][c]);
    }
    __syncthreads();
  }

#pragma unroll
  for (int r = 0; r < 8; ++r) {
    float* o = &sc[(((size_t)h * NT + (t0 + ty * 8 + r)) * 2 + p) * NKEY];
#pragma unroll
    for (int cp = 0; cp < 4; ++cp) {
      float2 st;
      st.x = acc[r][2 * cp];
      st.y = acc[r][2 * cp + 1];
      *reinterpret_cast<float2*>(&o[2 * tx + 64 * cp]) = st;
    }
  }
}

// ---------------------------------------------------------------------------
// K3: wave-per-(token,head) top-k. Merge trees restructured: within-half
// slot-merges (mergeslots) FIRST so the two wave halves merge different
// data; a single cross-half merge (mergehalf) last. Exact same top-32
// multiset and desc order as before (bitonic merges are exact; keys unique).
// ---------------------------------------------------------------------------
__device__ __forceinline__ u32 ford(float f) {
  u32 u = __float_as_uint(f);
  return u ^ (0x80000000u | (u32)((int)u >> 31));
}
__device__ __forceinline__ float funord(u32 o) {
  u32 b = (o & 0x80000000u) ? (o ^ 0x80000000u) : ~o;
  return __uint_as_float(b);
}

// Candidate down-set {(i,j): (i+1)*(j+1) <= 32}: 119 entries (c = i*32+j),
// padded to 128 with -1.
__device__ const short cand_tbl[128] = {
  0,1,2,3,4,5,6,7,8,9,10,11,12,13,14,15,16,17,18,19,20,21,22,23,24,25,26,27,28,29,30,31,
  32,33,34,35,36,37,38,39,40,41,42,43,44,45,46,47,
  64,65,66,67,68,69,70,71,72,73,
  96,97,98,99,100,101,102,103,
  128,129,130,131,132,133,
  160,161,162,163,164,
  192,193,194,195,
  224,225,226,227,
  256,257,258, 288,289,290,
  320,321, 352,353, 384,385, 416,417, 448,449, 480,481,
  512,544,576,608,640,672,704,736,768,800,832,864,896,928,960,992,
  -1,-1,-1,-1,-1,-1,-1,-1,-1
};

template <int NS>
__device__ __forceinline__ void sort32(u64* key, int i) {
#pragma unroll
  for (int k = 2; k <= 32; k <<= 1) {
#pragma unroll
    for (int j = k >> 1; j > 0; j >>= 1) {
      bool up = ((i & k) == 0);
#pragma unroll
      for (int r = 0; r < NS; ++r) {
        u64 o = __shfl_xor(key[r], j, 64);
        u64 mx = key[r] > o ? key[r] : o;
        u64 mn = key[r] < o ? key[r] : o;
        key[r] = (((i & j) == 0) == up) ? mx : mn;
      }
    }
  }
}

__device__ __forceinline__ u64 bmerge32(u64 a, int i) {
#pragma unroll
  for (int j = 16; j > 0; j >>= 1) {
    u64 o = __shfl_xor(a, j, 64);
    u64 mx = a > o ? a : o;
    u64 mn = a < o ? a : o;
    a = ((i & j) == 0) ? mx : mn;
  }
  return a;
}

// Merge the two desc lists living in the two wave halves of one slot,
// keeping the top-32; result replicated into both halves.
__device__ __forceinline__ u64 mergehalf(u64 a, int i) {
  u64 o = __shfl_xor(a, 63, 64);   // other half, reversed
  a = a > o ? a : o;
  return bmerge32(a, i);
}

// Merge two desc lists held in different regs on the same lanes (per-half
// independent), keep top-32 per half.
__device__ __forceinline__ u64 mergeslots(u64 a, u64 b, int i) {
  u64 o = __shfl_xor(b, 31, 64);   // b reversed within each half
  a = a > o ? a : o;
  return bmerge32(a, i);
}

__global__ __launch_bounds__(256) void k_topk(
    const float* __restrict__ sc, float* __restrict__ wout,
    int* __restrict__ vout) {
  const int t = blockIdx.x;
  const int lane = threadIdx.x & 63;
  const int h = threadIdx.x >> 6;
  const int i = lane & 31;

  u64 X, Y;
#pragma unroll
  for (int p = 0; p < 2; ++p) {
    const float* base = &sc[(((size_t)h * NT + t) * 2 + p) * NKEY];
    u64 key[4];
#pragma unroll
    for (int r = 0; r < 4; ++r) {
      int n = r * 64 + lane;
      key[r] = ((u64)ford(base[n]) << 32) | (u64)(0xFFFFFFFFu - (u32)n);
    }
    sort32<4>(key, i);                        // 8 sorted 32-chunks (r, half)
    u64 m01 = mergeslots(key[0], key[1], i);  // per-half slot merges
    u64 m23 = mergeslots(key[2], key[3], i);
    u64 mm  = mergeslots(m01, m23, i);        // per-half top32 of 4 chunks
    u64 m   = mergehalf(mm, i);               // cross-half: top32 of 256
    if (p == 0) X = m; else Y = m;
  }

  float xs = funord((u32)(X >> 32));
  float ys = funord((u32)(Y >> 32));
  u32 xn = 0xFFFFFFFFu - (u32)X;
  u32 yn = 0xFFFFFFFFu - (u32)Y;

  u64 s2[2];
#pragma unroll
  for (int r = 0; r < 2; ++r) {
    int ce = (int)cand_tbl[r * 64 + lane];
    int ci = (ce >= 0) ? (ce >> 5) : 0;
    int cj = (ce >= 0) ? (ce & 31) : 0;
    float sum = __shfl(xs, ci, 64) + __shfl(ys, cj, 64);  // fp32, as reference
    u64 kk = ((u64)ford(sum) << 32) | (u64)(0xFFFFFFFFu - (u32)ce);
    s2[r] = (ce >= 0) ? kk : 0ull;
  }
  sort32<2>(s2, i);                           // 4 sorted 32-lists (r, half)
  u64 uu = mergeslots(s2[0], s2[1], i);       // per-half merge
  u64 F  = mergehalf(uu, i);                  // top32 of all candidates

  float fs = funord((u32)(F >> 32));
  u32 c = 0xFFFFFFFFu - (u32)F;
  double m0 = (double)__shfl(fs, 0, 64);
  double e = exp((double)fs - m0);
  double ssum = e;
#pragma unroll
  for (int m = 1; m < 32; m <<= 1) ssum += __shfl_xor(ssum, m, 64);
  int ci = (int)(c >> 5), cj = (int)(c & 31);
  int nx = (int)__shfl(xn, ci, 64);
  int ny = (int)__shfl(yn, cj, 64);
  if (lane < 32) {
    wout[(size_t)(t * NH + h) * TK + lane] = (float)(e / ssum);
    vout[(size_t)(t * NH + h) * TK + lane] = nx * NKEY + ny;
  }
}

// ---------------------------------------------------------------------------
// K_cvt (fallback mode only): values f32 -> bf16 streaming.
// ---------------------------------------------------------------------------
__global__ __launch_bounds__(256) void k_cvt(
    const float* __restrict__ v, unsigned short* __restrict__ vb) {
  size_t i = (size_t)blockIdx.x * 256 + threadIdx.x;
  const size_t stride = (size_t)4096 * 256;
#pragma unroll
  for (int it = 0; it < 8; ++it) {
    size_t g = i + (size_t)it * stride;
    float4 a = reinterpret_cast<const float4*>(v)[g];
    ushort4 o;
    o.x = bfr(a.x); o.y = bfr(a.y); o.z = bfr(a.z); o.w = bfr(a.w);
    reinterpret_cast<ushort4*>(vb)[g] = o;
  }
}

// ---------------------------------------------------------------------------
// K4: weighted gather on bf16 values. (unchanged)
// ---------------------------------------------------------------------------
__global__ __launch_bounds__(256) void k_gather(
    const unsigned short* __restrict__ vb, const float* __restrict__ w,
    const int* __restrict__ vidx, float* __restrict__ out) {
  const int t = blockIdx.x;
  const int tid = threadIdx.x;
  const int wid = tid >> 6;
  const int lane = tid & 63;
  __shared__ float lw[128];
  __shared__ int lv[128];
  __shared__ float part[4][512];
  if (tid < 128) {
    lw[tid] = w[(size_t)t * 128 + tid];
    lv[tid] = vidx[(size_t)t * 128 + tid];
  }
  __syncthreads();
  float acc[8];
#pragma unroll
  for (int e = 0; e < 8; ++e) acc[e] = 0.f;
  const int jb = wid * 32;
#pragma unroll 8
  for (int k = 0; k < 32; ++k) {
    float wj = lw[jb + k];
    const uint4 v = *reinterpret_cast<const uint4*>(
        &vb[(size_t)lv[jb + k] * DIMC + lane * 8]);
    acc[0] = fmaf(wj, __uint_as_float(v.x << 16), acc[0]);
    acc[1] = fmaf(wj, __uint_as_float(v.x & 0xffff0000u), acc[1]);
    acc[2] = fmaf(wj, __uint_as_float(v.y << 16), acc[2]);
    acc[3] = fmaf(wj, __uint_as_float(v.y & 0xffff0000u), acc[3]);
    acc[4] = fmaf(wj, __uint_as_float(v.z << 16), acc[4]);
    acc[5] = fmaf(wj, __uint_as_float(v.z & 0xffff0000u), acc[5]);
    acc[6] = fmaf(wj, __uint_as_float(v.w << 16), acc[6]);
    acc[7] = fmaf(wj, __uint_as_float(v.w & 0xffff0000u), acc[7]);
  }
  float4* pp = reinterpret_cast<float4*>(&part[wid][lane * 8]);
  pp[0] = make_float4(acc[0], acc[1], acc[2], acc[3]);
  pp[1] = make_float4(acc[4], acc[5], acc[6], acc[7]);
  __syncthreads();
  int d = tid * 2;
  float2 o;
  o.x = (part[0][d]     + part[1][d])     + (part[2][d]     + part[3][d]);
  o.y = (part[0][d + 1] + part[1][d + 1]) + (part[2][d + 1] + part[3][d + 1]);
  *reinterpret_cast<float2*>(&out[(size_t)t * DIMC + d]) = o;
}

// ---------------------------------------------------------------------------
// Workspace:
//  overlap mode (ws >= 116 MB): qn[0,16) sc[16,48) vb[48,112) wv[112,114) vi[114,116)
//    k_qproj_cvt(512+1024 blocks) -> k_dots -> k_topk -> k_gather
//  fallback (ws >= 68 MB): vb[0,64) aliases qn[0,16)+sc[16,48); wv[64,66) vi[66,68)
//    k_qproj_cvt(512 blocks, nCvt=0) -> k_dots -> k_topk -> k_cvt -> k_gather
// Branch depends only on ws_size (launch-constant): graph-safe.
// ---------------------------------------------------------------------------
extern "C" void kernel_launch(void* const* d_in, const int* in_sizes, int n_in,
                              void* d_out, int out_size, void* d_ws, size_t ws_size,
                              hipStream_t stream) {
  const float* x      = (const float*)d_in[0];
  const float* wq     = (const float*)d_in[1];
  const float* ln_g   = (const float*)d_in[2];
  const float* ln_b   = (const float*)d_in[3];
  const float* keys   = (const float*)d_in[4];
  const float* values = (const float*)d_in[5];
  float* out = (float*)d_out;

  char* ws = (char*)d_ws;
  const bool overlap = ws_size >= (size_t)116 * 1024 * 1024;

  float* qn = (float*)ws;                         // 16 MB
  float* sc = (float*)(ws + (16ull << 20));       // 32 MB
  unsigned short* vb;
  float* wv;
  int*   vi;
  if (overlap) {
    vb = (unsigned short*)(ws + (48ull << 20));   // 64 MB
    wv = (float*)(ws + (112ull << 20));
    vi = (int*)(ws + (114ull << 20));
  } else {
    vb = (unsigned short*)ws;                     // aliases qn+sc (written late)
    wv = (float*)(ws + (64ull << 20));
    vi = (int*)(ws + (66ull << 20));
  }

  const int nCvt = overlap ? 1024 : 0;
  k_qproj_cvt<<<dim3(512 + nCvt), 256, 0, stream>>>(
      x, wq, ln_g, ln_b, qn, values, vb, nCvt);
  k_dots<<<dim3(64, 2, 4), 256, 0, stream>>>(qn, keys, sc);
  k_topk<<<dim3(4096), 256, 0, stream>>>(sc, wv, vi);
  if (!overlap) k_cvt<<<dim3(4096), 256, 0, stream>>>(values, vb);
  k_gather<<<dim3(4096), 256, 0, stream>>>(vb, wv, vi, out);
}